// Round 8
// baseline (72.643 us; speedup 1.0000x reference)
//
#include <hip/hip_runtime.h>
#include <hip/hip_bf16.h>

#define DM   1024
#define DH   128
#define DL   64
#define NTOK 8192
#define NEXP 65536
#define HK   32

typedef __attribute__((ext_vector_type(4))) float f32x4;
typedef __attribute__((ext_vector_type(8))) short bf16x8;

__device__ __forceinline__ float gelu_sig(float v) {
    return v * __builtin_amdgcn_rcpf(1.0f + __expf(-1.702f * v));
}

__device__ __forceinline__ unsigned short f2bf(float f) {
    union { float f; unsigned u; } v; v.f = f;
    unsigned r = v.u + 0x7FFFu + ((v.u >> 16) & 1u);   // RNE
    return (unsigned short)(r >> 16);
}

__device__ __forceinline__ bf16x8 pack8(const float4& a, const float4& b) {
    bf16x8 r;
    r[0] = (short)f2bf(a.x); r[1] = (short)f2bf(a.y);
    r[2] = (short)f2bf(a.z); r[3] = (short)f2bf(a.w);
    r[4] = (short)f2bf(b.x); r[5] = (short)f2bf(b.y);
    r[6] = (short)f2bf(b.z); r[7] = (short)f2bf(b.w);
    return r;
}

// ---------------- Kernel P: transpose+convert Wu -> Wut[c][k], W1 -> W1T[c][k] ----------------
__global__ __launch_bounds__(256) void k_prep(const float* __restrict__ Wu,
                                              const float* __restrict__ W1,
                                              unsigned short* __restrict__ Wut,
                                              unsigned short* __restrict__ W1T) {
    const int b = blockIdx.x, t = threadIdx.x;
    if (b < 512) {                       // Wut: 128 x 1024
        const int i = b * 256 + t;
        const int c = i >> 10, k = i & 1023;
        Wut[i] = f2bf(Wu[k * DH + c]);
    } else {                             // W1T: 128 x 64
        const int j = (b - 512) * 256 + t;
        const int c = j >> 6, k = j & 63;
        W1T[j] = f2bf(W1[k * DH + c]);
    }
}

// ---------------- Kernel A: xproj = x @ Wu via bf16 MFMA ----------------
// grid (NTOK/32, 2): 32 rows x 64 cols per block; 4 waves, each 16 cols (N_rep=1, M_rep=2).
__global__ __launch_bounds__(256) void k_xproj(const float* __restrict__ x,
                                               const unsigned short* __restrict__ Wut,
                                               float* __restrict__ xproj) {
    __shared__ unsigned short As[32][72];    // 32 rows x 64 k (+8 pad)
    __shared__ unsigned short Bs[64][72];    // 64 cols x 64 k (+8 pad)
    const int t = threadIdx.x;
    const int w = t >> 6, l = t & 63;
    const int fr = l & 15, fh = l >> 4;
    const int row0 = blockIdx.x * 32;
    const int cb = blockIdx.y * 64;
    const int ar = t >> 3, ac = (t & 7) * 8;     // A: 8 floats/thread (32x64)
    const int bc = t >> 2, bk = (t & 3) * 16;    // B: 16 bf16/thread (64x64)

    f32x4 acc[2] = {};
    float4 a0, a1; bf16x8 b0, b1;

    a0 = *(const float4*)&x[(size_t)(row0 + ar) * DM + ac];
    a1 = *(const float4*)&x[(size_t)(row0 + ar) * DM + ac + 4];
    b0 = *(const bf16x8*)&Wut[(size_t)(cb + bc) * DM + bk];
    b1 = *(const bf16x8*)&Wut[(size_t)(cb + bc) * DM + bk + 8];

    for (int it = 0; it < DM / 64; ++it) {
        if (it) __syncthreads();
        *(bf16x8*)&As[ar][ac]     = pack8(a0, a1);
        *(bf16x8*)&Bs[bc][bk]     = b0;
        *(bf16x8*)&Bs[bc][bk + 8] = b1;
        __syncthreads();
        if (it < DM / 64 - 1) {
            const int kc = (it + 1) * 64;
            a0 = *(const float4*)&x[(size_t)(row0 + ar) * DM + kc + ac];
            a1 = *(const float4*)&x[(size_t)(row0 + ar) * DM + kc + ac + 4];
            b0 = *(const bf16x8*)&Wut[(size_t)(cb + bc) * DM + kc + bk];
            b1 = *(const bf16x8*)&Wut[(size_t)(cb + bc) * DM + kc + bk + 8];
        }
        #pragma unroll
        for (int kk = 0; kk < 2; ++kk) {
            bf16x8 bv = *(bf16x8*)&Bs[w * 16 + fr][kk * 32 + fh * 8];
            #pragma unroll
            for (int m = 0; m < 2; ++m) {
                bf16x8 av = *(bf16x8*)&As[m * 16 + fr][kk * 32 + fh * 8];
                acc[m] = __builtin_amdgcn_mfma_f32_16x16x32_bf16(av, bv, acc[m], 0, 0, 0);
            }
        }
    }
    #pragma unroll
    for (int m = 0; m < 2; ++m)
        #pragma unroll
        for (int r = 0; r < 4; ++r)
            xproj[(size_t)(row0 + m * 16 + fh * 4 + r) * DH + cb + w * 16 + fr] =
                acc[m][r];
}

// ---------------- Kernel C: wave-per-token gather+h+dot+accumulate (no LDS, no barriers) ----------------
// One wave computes token n's full 32x128 h tile via MFMA with A-frags loaded
// directly from lat (global), then does both reductions with shfl_xor.
// h-tile layout per lane l=(fr,fh): acc[m][n2][r] = h[s][f], s=m*16+fh*4+r, f=n2*16+fr.
__global__ __launch_bounds__(256) void k_gather(const float* __restrict__ xproj,
                                                const float* __restrict__ scores,
                                                const int* __restrict__ idx,
                                                const float* __restrict__ lat,
                                                const unsigned short* __restrict__ W1T,
                                                float* __restrict__ accout) {
    const int t = threadIdx.x;
    const int n = blockIdx.x * 4 + (t >> 6);
    const int l = t & 63;
    const int fr = l & 15, fh = l >> 4;

    // A fragments: rows s=m*16+fr, k=kk*32+fh*8 (direct global load, fp32->bf16)
    const int e0 = idx[n * HK + fr];
    const int e1 = idx[n * HK + 16 + fr];
    bf16x8 av[2][2];
    {
        const float* rp = &lat[(size_t)e0 * DL + fh * 8];
        av[0][0] = pack8(*(const float4*)&rp[0],  *(const float4*)&rp[4]);
        av[0][1] = pack8(*(const float4*)&rp[32], *(const float4*)&rp[36]);
        rp = &lat[(size_t)e1 * DL + fh * 8];
        av[1][0] = pack8(*(const float4*)&rp[0],  *(const float4*)&rp[4]);
        av[1][1] = pack8(*(const float4*)&rp[32], *(const float4*)&rp[36]);
    }

    // xproj values this lane needs for the dot phase
    float xpv[8];
    #pragma unroll
    for (int n2 = 0; n2 < 8; ++n2)
        xpv[n2] = xproj[(size_t)n * DH + n2 * 16 + fr];

    // MFMA: 32x128x64, B-frags from W1T chunked by kk to bound VGPR pressure
    f32x4 acc[2][8] = {};
    #pragma unroll
    for (int kk = 0; kk < 2; ++kk) {
        bf16x8 bk[8];
        #pragma unroll
        for (int n2 = 0; n2 < 8; ++n2)
            bk[n2] = *(const bf16x8*)&W1T[(size_t)(n2 * 16 + fr) * DL + kk * 32 + fh * 8];
        #pragma unroll
        for (int m = 0; m < 2; ++m)
            #pragma unroll
            for (int n2 = 0; n2 < 8; ++n2)
                acc[m][n2] = __builtin_amdgcn_mfma_f32_16x16x32_bf16(
                    av[m][kk], bk[n2], acc[m][n2], 0, 0, 0);
    }

    // gelu in-register (overwrite acc with h)
    #pragma unroll
    for (int m = 0; m < 2; ++m)
        #pragma unroll
        for (int n2 = 0; n2 < 8; ++n2)
            #pragma unroll
            for (int r = 0; r < 4; ++r)
                acc[m][n2][r] = gelu_sig(acc[m][n2][r]);

    // dots + act: s's rows live in this fh-group's 16 lanes; reduce over fr
    float act[2][4];
    #pragma unroll
    for (int m = 0; m < 2; ++m)
        #pragma unroll
        for (int r = 0; r < 4; ++r) {
            float p = 0.0f;
            #pragma unroll
            for (int n2 = 0; n2 < 8; ++n2)
                p = fmaf(acc[m][n2][r], xpv[n2], p);
            p += __shfl_xor(p, 1, 64);
            p += __shfl_xor(p, 2, 64);
            p += __shfl_xor(p, 4, 64);
            p += __shfl_xor(p, 8, 64);
            const int s = m * 16 + fh * 4 + r;
            act[m][r] = gelu_sig(p) * scores[n * HK + s];
        }

    // accumulate: partial over this lane's 8 s, reduce over fh (xor 16,32)
    #pragma unroll
    for (int n2 = 0; n2 < 8; ++n2) {
        float a = 0.0f;
        #pragma unroll
        for (int m = 0; m < 2; ++m)
            #pragma unroll
            for (int r = 0; r < 4; ++r)
                a = fmaf(act[m][r], acc[m][n2][r], a);
        a += __shfl_xor(a, 16, 64);
        a += __shfl_xor(a, 32, 64);
        if (fh == 0)
            accout[(size_t)n * DH + n2 * 16 + fr] = a;
    }
}

// ---------------- Kernel D: out = (acc @ Wv)/4 via bf16 MFMA ----------------
// BM=64, BN=128, K=128 single-shot; grid (128, 8); M_rep=4, N_rep=2.
__global__ __launch_bounds__(256) void k_out(const float* __restrict__ acc,
                                             const float* __restrict__ Wv,
                                             float* __restrict__ out) {
    __shared__ unsigned short As[64][136];   // 64 rows x 128 k (+8 pad)
    const int t = threadIdx.x;
    const int w = t >> 6, l = t & 63;
    const int fr = l & 15, fh = l >> 4;
    const int row0 = blockIdx.x * 64;
    const int c0 = blockIdx.y * 128;
    const int ar = t >> 2, ac = (t & 3) * 32;    // 32 floats/thread (64x128)

    {
        const float* src = &acc[(size_t)(row0 + ar) * DH + ac];
        #pragma unroll
        for (int j = 0; j < 4; ++j) {
            float4 v0 = *(const float4*)&src[j * 8];
            float4 v1 = *(const float4*)&src[j * 8 + 4];
            *(bf16x8*)&As[ar][ac + j * 8] = pack8(v0, v1);
        }
    }
    bf16x8 bv[2][4];                         // [n][kk]
    #pragma unroll
    for (int n = 0; n < 2; ++n)
        #pragma unroll
        for (int kk = 0; kk < 4; ++kk)
            #pragma unroll
            for (int b = 0; b < 8; ++b)
                bv[n][kk][b] = (short)f2bf(
                    Wv[(size_t)(kk * 32 + fh * 8 + b) * DM + c0 + w * 32 + n * 16 + fr]);
    __syncthreads();

    f32x4 o[4][2] = {};
    #pragma unroll
    for (int kk = 0; kk < 4; ++kk)
        #pragma unroll
        for (int m = 0; m < 4; ++m) {
            bf16x8 av = *(bf16x8*)&As[m * 16 + fr][kk * 32 + fh * 8];
            #pragma unroll
            for (int n = 0; n < 2; ++n)
                o[m][n] = __builtin_amdgcn_mfma_f32_16x16x32_bf16(
                    av, bv[n][kk], o[m][n], 0, 0, 0);
        }
    #pragma unroll
    for (int m = 0; m < 4; ++m)
        #pragma unroll
        for (int n = 0; n < 2; ++n)
            #pragma unroll
            for (int r = 0; r < 4; ++r)
                out[(size_t)(row0 + m * 16 + fh * 4 + r) * DM + c0 + w * 32 + n * 16 + fr] =
                    o[m][n][r] * 0.25f;
}

extern "C" void kernel_launch(void* const* d_in, const int* in_sizes, int n_in,
                              void* d_out, int out_size, void* d_ws, size_t ws_size,
                              hipStream_t stream) {
    const float* x      = (const float*)d_in[0];
    const float* scores = (const float*)d_in[1];
    const int*   idx    = (const int*)d_in[2];
    const float* lat    = (const float*)d_in[3];
    const float* W1     = (const float*)d_in[4];
    const float* Wu     = (const float*)d_in[5];
    const float* Wv     = (const float*)d_in[6];
    float* out = (float*)d_out;

    float* xproj  = (float*)d_ws;                            // 8192*128 f32 (4 MB)
    float* accbuf = xproj + (size_t)NTOK * DH;               // 8192*128 f32 (4 MB)
    unsigned short* Wut = (unsigned short*)(accbuf + (size_t)NTOK * DH);  // 128x1024 bf16 (256 KB)
    unsigned short* W1T = Wut + (size_t)DH * DM;             // 128x64 bf16 (16 KB)

    k_prep<<<512 + 32, 256, 0, stream>>>(Wu, W1, Wut, W1T);
    k_xproj<<<dim3(NTOK / 32, 2), 256, 0, stream>>>(x, Wut, xproj);
    k_gather<<<NTOK / 4, 256, 0, stream>>>(xproj, scores, idx, lat, W1T, accbuf);
    k_out<<<dim3(NTOK / 64, DM / 128), 256, 0, stream>>>(accbuf, Wv, out);
}

// Round 9
// 63.225 us; speedup vs baseline: 1.1490x; 1.1490x over previous
//
#include <hip/hip_runtime.h>
#include <hip/hip_bf16.h>

#define DM   1024
#define DH   128
#define DL   64
#define NTOK 8192
#define NEXP 65536
#define HK   32

typedef __attribute__((ext_vector_type(4))) float f32x4;
typedef __attribute__((ext_vector_type(8))) short bf16x8;

__device__ __forceinline__ float gelu_sig(float v) {
    return v * __builtin_amdgcn_rcpf(1.0f + __expf(-1.702f * v));
}

__device__ __forceinline__ unsigned short f2bf(float f) {
    union { float f; unsigned u; } v; v.f = f;
    unsigned r = v.u + 0x7FFFu + ((v.u >> 16) & 1u);   // RNE
    return (unsigned short)(r >> 16);
}

__device__ __forceinline__ float bf2f(unsigned short h) {
    union { unsigned u; float f; } v; v.u = ((unsigned)h) << 16;
    return v.f;
}

__device__ __forceinline__ bf16x8 pack8(const float4& a, const float4& b) {
    bf16x8 r;
    r[0] = (short)f2bf(a.x); r[1] = (short)f2bf(a.y);
    r[2] = (short)f2bf(a.z); r[3] = (short)f2bf(a.w);
    r[4] = (short)f2bf(b.x); r[5] = (short)f2bf(b.y);
    r[6] = (short)f2bf(b.z); r[7] = (short)f2bf(b.w);
    return r;
}

// ---------------- Kernel P: transpose+convert Wu -> Wut[c][k], W1 -> W1T[c][k] ----------------
__global__ __launch_bounds__(256) void k_prep(const float* __restrict__ Wu,
                                              const float* __restrict__ W1,
                                              unsigned short* __restrict__ Wut,
                                              unsigned short* __restrict__ W1T) {
    const int b = blockIdx.x, t = threadIdx.x;
    if (b < 512) {                       // Wut: 128 x 1024
        const int i = b * 256 + t;
        const int c = i >> 10, k = i & 1023;
        Wut[i] = f2bf(Wu[k * DH + c]);
    } else {                             // W1T: 128 x 64
        const int j = (b - 512) * 256 + t;
        const int c = j >> 6, k = j & 63;
        W1T[j] = f2bf(W1[k * DH + c]);
    }
}

// ---------------- Kernel A: xproj = x @ Wu via bf16 MFMA (round-7 verbatim) ----------------
__global__ __launch_bounds__(256) void k_xproj(const float* __restrict__ x,
                                               const unsigned short* __restrict__ Wut,
                                               float* __restrict__ xproj) {
    __shared__ unsigned short As[32][72];
    __shared__ unsigned short Bs[64][72];
    const int t = threadIdx.x;
    const int w = t >> 6, l = t & 63;
    const int fr = l & 15, fh = l >> 4;
    const int row0 = blockIdx.x * 32;
    const int cb = blockIdx.y * 64;
    const int ar = t >> 3, ac = (t & 7) * 8;
    const int bc = t >> 2, bk = (t & 3) * 16;

    f32x4 acc[2] = {};
    float4 a0, a1; bf16x8 b0, b1;

    a0 = *(const float4*)&x[(size_t)(row0 + ar) * DM + ac];
    a1 = *(const float4*)&x[(size_t)(row0 + ar) * DM + ac + 4];
    b0 = *(const bf16x8*)&Wut[(size_t)(cb + bc) * DM + bk];
    b1 = *(const bf16x8*)&Wut[(size_t)(cb + bc) * DM + bk + 8];

    for (int it = 0; it < DM / 64; ++it) {
        if (it) __syncthreads();
        *(bf16x8*)&As[ar][ac]     = pack8(a0, a1);
        *(bf16x8*)&Bs[bc][bk]     = b0;
        *(bf16x8*)&Bs[bc][bk + 8] = b1;
        __syncthreads();
        if (it < DM / 64 - 1) {
            const int kc = (it + 1) * 64;
            a0 = *(const float4*)&x[(size_t)(row0 + ar) * DM + kc + ac];
            a1 = *(const float4*)&x[(size_t)(row0 + ar) * DM + kc + ac + 4];
            b0 = *(const bf16x8*)&Wut[(size_t)(cb + bc) * DM + kc + bk];
            b1 = *(const bf16x8*)&Wut[(size_t)(cb + bc) * DM + kc + bk + 8];
        }
        #pragma unroll
        for (int kk = 0; kk < 2; ++kk) {
            bf16x8 bv = *(bf16x8*)&Bs[w * 16 + fr][kk * 32 + fh * 8];
            #pragma unroll
            for (int m = 0; m < 2; ++m) {
                bf16x8 av = *(bf16x8*)&As[m * 16 + fr][kk * 32 + fh * 8];
                acc[m] = __builtin_amdgcn_mfma_f32_16x16x32_bf16(av, bv, acc[m], 0, 0, 0);
            }
        }
    }
    #pragma unroll
    for (int m = 0; m < 2; ++m)
        #pragma unroll
        for (int r = 0; r < 4; ++r)
            xproj[(size_t)(row0 + m * 16 + fh * 4 + r) * DH + cb + w * 16 + fr] =
                acc[m][r];
}

// ---------------- Kernel B: Hallb = bf16(gelu(lat @ W1)) for ALL experts ----------------
// grid NEXP/64. MFMA as round 4; epilogue transposes via LDS for coalesced bf16 stores.
__global__ __launch_bounds__(256) void k_hall(const float* __restrict__ lat,
                                              const unsigned short* __restrict__ W1T,
                                              unsigned short* __restrict__ Hallb) {
    __shared__ unsigned short As[64][72];    // 64 experts x 64 latent (+8 pad)
    __shared__ float Hs[64][132];            // h fp32 staging (+4 pad)
    const int t = threadIdx.x;
    const int w = t >> 6, l = t & 63;
    const int fr = l & 15, fh = l >> 4;
    const int e0 = blockIdx.x * 64;
    const int ar = t >> 2, ac = (t & 3) * 16;    // 16 floats/thread (64x64)

    {
        const float* src = &lat[(size_t)(e0 + ar) * DL + ac];
        float4 v0 = *(const float4*)&src[0],  v1 = *(const float4*)&src[4];
        float4 v2 = *(const float4*)&src[8],  v3 = *(const float4*)&src[12];
        *(bf16x8*)&As[ar][ac]     = pack8(v0, v1);
        *(bf16x8*)&As[ar][ac + 8] = pack8(v2, v3);
    }
    bf16x8 bv[2][2];                          // [n2][kk]
    #pragma unroll
    for (int n2 = 0; n2 < 2; ++n2)
        #pragma unroll
        for (int kk = 0; kk < 2; ++kk)
            bv[n2][kk] = *(const bf16x8*)
                &W1T[(size_t)(w * 32 + n2 * 16 + fr) * DL + kk * 32 + fh * 8];
    __syncthreads();

    f32x4 acc[4][2] = {};
    #pragma unroll
    for (int kk = 0; kk < 2; ++kk)
        #pragma unroll
        for (int m = 0; m < 4; ++m) {
            bf16x8 av = *(bf16x8*)&As[m * 16 + fr][kk * 32 + fh * 8];
            #pragma unroll
            for (int n2 = 0; n2 < 2; ++n2)
                acc[m][n2] = __builtin_amdgcn_mfma_f32_16x16x32_bf16(
                    av, bv[n2][kk], acc[m][n2], 0, 0, 0);
        }
    #pragma unroll
    for (int m = 0; m < 4; ++m)
        #pragma unroll
        for (int n2 = 0; n2 < 2; ++n2)
            #pragma unroll
            for (int r = 0; r < 4; ++r)
                Hs[m * 16 + fh * 4 + r][w * 32 + n2 * 16 + fr] =
                    gelu_sig(acc[m][n2][r]);
    __syncthreads();

    // pack 64x128 fp32 -> bf16, coalesced 16B stores
    #pragma unroll
    for (int j = 0; j < 4; ++j) {
        const int chunk = t + j * 256;        // 1024 chunks of 8
        const int row = chunk >> 4, c8 = (chunk & 15) * 8;
        float4 a = *(float4*)&Hs[row][c8];
        float4 b = *(float4*)&Hs[row][c8 + 4];
        *(bf16x8*)&Hallb[(size_t)(e0 + row) * DH + c8] = pack8(a, b);
    }
}

// ---------------- Kernel C: gather Hall rows + dot + act + accumulate ----------------
__global__ __launch_bounds__(256) void k_gather(const float* __restrict__ xproj,
                                                const float* __restrict__ scores,
                                                const int* __restrict__ idx,
                                                const unsigned short* __restrict__ Hallb,
                                                float* __restrict__ accout) {
    __shared__ float Hs[HK][132];            // 32 sel x 128 hidden fp32 (+4 pad)
    __shared__ float xp[132];
    __shared__ float acts[HK];
    __shared__ float psum[DH];
    const int n = blockIdx.x;
    const int t = threadIdx.x;
    const int w = t >> 6;

    // Phase A: gather Hall bf16 rows -> fp32 LDS (row = t>>3, 16 cols/thread)
    {
        const int row = t >> 3, c0 = (t & 7) * 16;
        const int e = idx[n * HK + row];          // 8-way broadcast
        const unsigned short* src = &Hallb[(size_t)e * DH + c0];
        bf16x8 v0 = *(const bf16x8*)&src[0];
        bf16x8 v1 = *(const bf16x8*)&src[8];
        float o[16];
        #pragma unroll
        for (int i = 0; i < 8; ++i) {
            o[i]     = bf2f((unsigned short)v0[i]);
            o[i + 8] = bf2f((unsigned short)v1[i]);
        }
        *(float4*)&Hs[row][c0]      = *(float4*)&o[0];
        *(float4*)&Hs[row][c0 + 4]  = *(float4*)&o[4];
        *(float4*)&Hs[row][c0 + 8]  = *(float4*)&o[8];
        *(float4*)&Hs[row][c0 + 12] = *(float4*)&o[12];
    }
    if (t < 128) xp[t] = xproj[(size_t)n * DH + t];
    __syncthreads();

    // Phase C: dots. s = t>>3 (32 sels), j = t&7 owns f = j*16..+15.
    {
        const int s = t >> 3, j = t & 7, f0 = j * 16;
        float part = 0.0f;
        #pragma unroll
        for (int k = 0; k < 4; ++k) {
            float4 hv = *(float4*)&Hs[s][f0 + k * 4];
            float4 xv = *(float4*)&xp[f0 + k * 4];
            part = fmaf(hv.x, xv.x, part);
            part = fmaf(hv.y, xv.y, part);
            part = fmaf(hv.z, xv.z, part);
            part = fmaf(hv.w, xv.w, part);
        }
        part += __shfl_xor(part, 1, 64);
        part += __shfl_xor(part, 2, 64);
        part += __shfl_xor(part, 4, 64);
        float a = gelu_sig(part) * scores[n * HK + s];
        if (j == 0) acts[s] = a;
    }
    __syncthreads();

    // Phase D: accout[f] = sum_s acts[s]*Hs[s][f]; f = t&127, half hh = t>>7.
    {
        const int f = t & 127, hh = t >> 7;
        float a = 0.0f;
        #pragma unroll
        for (int s8 = 0; s8 < 16; ++s8) {
            int s = hh * 16 + s8;
            a = fmaf(acts[s], Hs[s][f], a);
        }
        if (hh) psum[f] = a;
        __syncthreads();
        if (!hh) accout[(size_t)n * DH + f] = a + psum[f];
    }
    (void)w;
}

// ---------------- Kernel D: out = (acc @ Wv)/4 via bf16 MFMA (round-7 verbatim) ----------------
__global__ __launch_bounds__(256) void k_out(const float* __restrict__ acc,
                                             const float* __restrict__ Wv,
                                             float* __restrict__ out) {
    __shared__ unsigned short As[64][136];
    const int t = threadIdx.x;
    const int w = t >> 6, l = t & 63;
    const int fr = l & 15, fh = l >> 4;
    const int row0 = blockIdx.x * 64;
    const int c0 = blockIdx.y * 128;
    const int ar = t >> 2, ac = (t & 3) * 32;

    {
        const float* src = &acc[(size_t)(row0 + ar) * DH + ac];
        #pragma unroll
        for (int j = 0; j < 4; ++j) {
            float4 v0 = *(const float4*)&src[j * 8];
            float4 v1 = *(const float4*)&src[j * 8 + 4];
            *(bf16x8*)&As[ar][ac + j * 8] = pack8(v0, v1);
        }
    }
    bf16x8 bv[2][4];
    #pragma unroll
    for (int n = 0; n < 2; ++n)
        #pragma unroll
        for (int kk = 0; kk < 4; ++kk)
            #pragma unroll
            for (int b = 0; b < 8; ++b)
                bv[n][kk][b] = (short)f2bf(
                    Wv[(size_t)(kk * 32 + fh * 8 + b) * DM + c0 + w * 32 + n * 16 + fr]);
    __syncthreads();

    f32x4 o[4][2] = {};
    #pragma unroll
    for (int kk = 0; kk < 4; ++kk)
        #pragma unroll
        for (int m = 0; m < 4; ++m) {
            bf16x8 av = *(bf16x8*)&As[m * 16 + fr][kk * 32 + fh * 8];
            #pragma unroll
            for (int n = 0; n < 2; ++n)
                o[m][n] = __builtin_amdgcn_mfma_f32_16x16x32_bf16(
                    av, bv[n][kk], o[m][n], 0, 0, 0);
        }
    #pragma unroll
    for (int m = 0; m < 4; ++m)
        #pragma unroll
        for (int n = 0; n < 2; ++n)
            #pragma unroll
            for (int r = 0; r < 4; ++r)
                out[(size_t)(row0 + m * 16 + fh * 4 + r) * DM + c0 + w * 32 + n * 16 + fr] =
                    o[m][n][r] * 0.25f;
}

extern "C" void kernel_launch(void* const* d_in, const int* in_sizes, int n_in,
                              void* d_out, int out_size, void* d_ws, size_t ws_size,
                              hipStream_t stream) {
    const float* x      = (const float*)d_in[0];
    const float* scores = (const float*)d_in[1];
    const int*   idx    = (const int*)d_in[2];
    const float* lat    = (const float*)d_in[3];
    const float* W1     = (const float*)d_in[4];
    const float* Wu     = (const float*)d_in[5];
    const float* Wv     = (const float*)d_in[6];
    float* out = (float*)d_out;

    float* xproj  = (float*)d_ws;                            // 8192*128 f32 (4 MB)
    float* accbuf = xproj + (size_t)NTOK * DH;               // 8192*128 f32 (4 MB)
    unsigned short* Wut = (unsigned short*)(accbuf + (size_t)NTOK * DH);  // 256 KB
    unsigned short* W1T = Wut + (size_t)DH * DM;             // 16 KB
    unsigned short* Hallb = W1T + (size_t)DH * DL;           // 65536*128 bf16 (16.8 MB)

    k_prep<<<512 + 32, 256, 0, stream>>>(Wu, W1, Wut, W1T);
    k_xproj<<<dim3(NTOK / 32, 2), 256, 0, stream>>>(x, Wut, xproj);
    k_hall<<<NEXP / 64, 256, 0, stream>>>(lat, W1T, Hallb);
    k_gather<<<NTOK, 256, 0, stream>>>(xproj, scores, idx, Hallb, accbuf);
    k_out<<<dim3(NTOK / 64, DM / 128), 256, 0, stream>>>(accbuf, Wv, out);
}

// Round 10
// 60.200 us; speedup vs baseline: 1.2067x; 1.0502x over previous
//
#include <hip/hip_runtime.h>
#include <hip/hip_bf16.h>

#define DM   1024
#define DH   128
#define DL   64
#define NTOK 8192
#define NEXP 65536
#define HK   32

typedef __attribute__((ext_vector_type(4))) float f32x4;
typedef __attribute__((ext_vector_type(8))) short bf16x8;

__device__ __forceinline__ float gelu_sig(float v) {
    return v * __builtin_amdgcn_rcpf(1.0f + __expf(-1.702f * v));
}

__device__ __forceinline__ unsigned short f2bf(float f) {
    union { float f; unsigned u; } v; v.f = f;
    unsigned r = v.u + 0x7FFFu + ((v.u >> 16) & 1u);   // RNE
    return (unsigned short)(r >> 16);
}

__device__ __forceinline__ bf16x8 pack8(const float4& a, const float4& b) {
    bf16x8 r;
    r[0] = (short)f2bf(a.x); r[1] = (short)f2bf(a.y);
    r[2] = (short)f2bf(a.z); r[3] = (short)f2bf(a.w);
    r[4] = (short)f2bf(b.x); r[5] = (short)f2bf(b.y);
    r[6] = (short)f2bf(b.z); r[7] = (short)f2bf(b.w);
    return r;
}

// ---------------- Kernel P: Wut/W1T transposed bf16 tables + latb bf16 table ----------------
__global__ __launch_bounds__(256) void k_prep(const float* __restrict__ Wu,
                                              const float* __restrict__ W1,
                                              const float* __restrict__ lat,
                                              unsigned short* __restrict__ Wut,
                                              unsigned short* __restrict__ W1T,
                                              unsigned short* __restrict__ latb) {
    const int b = blockIdx.x, t = threadIdx.x;
    if (b < 512) {                       // Wut: 128 x 1024 (transpose)
        const int i = b * 256 + t;
        const int c = i >> 10, k = i & 1023;
        Wut[i] = f2bf(Wu[k * DH + c]);
    } else if (b < 544) {                // W1T: 128 x 64 (transpose)
        const int j = (b - 512) * 256 + t;
        const int c = j >> 6, k = j & 63;
        W1T[j] = f2bf(W1[k * DH + c]);
    } else {                             // latb: straight bf16 convert, 8 elems/thread
        const size_t base = ((size_t)(b - 544) * 256 + t) * 8;
        float4 v0 = *(const float4*)&lat[base];
        float4 v1 = *(const float4*)&lat[base + 4];
        *(bf16x8*)&latb[base] = pack8(v0, v1);
    }
}

// ---------------- Kernel A: xproj = x @ Wu via bf16 MFMA (round-7 verbatim) ----------------
__global__ __launch_bounds__(256) void k_xproj(const float* __restrict__ x,
                                               const unsigned short* __restrict__ Wut,
                                               float* __restrict__ xproj) {
    __shared__ unsigned short As[32][72];
    __shared__ unsigned short Bs[64][72];
    const int t = threadIdx.x;
    const int w = t >> 6, l = t & 63;
    const int fr = l & 15, fh = l >> 4;
    const int row0 = blockIdx.x * 32;
    const int cb = blockIdx.y * 64;
    const int ar = t >> 3, ac = (t & 7) * 8;
    const int bc = t >> 2, bk = (t & 3) * 16;

    f32x4 acc[2] = {};
    float4 a0, a1; bf16x8 b0, b1;

    a0 = *(const float4*)&x[(size_t)(row0 + ar) * DM + ac];
    a1 = *(const float4*)&x[(size_t)(row0 + ar) * DM + ac + 4];
    b0 = *(const bf16x8*)&Wut[(size_t)(cb + bc) * DM + bk];
    b1 = *(const bf16x8*)&Wut[(size_t)(cb + bc) * DM + bk + 8];

    for (int it = 0; it < DM / 64; ++it) {
        if (it) __syncthreads();
        *(bf16x8*)&As[ar][ac]     = pack8(a0, a1);
        *(bf16x8*)&Bs[bc][bk]     = b0;
        *(bf16x8*)&Bs[bc][bk + 8] = b1;
        __syncthreads();
        if (it < DM / 64 - 1) {
            const int kc = (it + 1) * 64;
            a0 = *(const float4*)&x[(size_t)(row0 + ar) * DM + kc + ac];
            a1 = *(const float4*)&x[(size_t)(row0 + ar) * DM + kc + ac + 4];
            b0 = *(const bf16x8*)&Wut[(size_t)(cb + bc) * DM + kc + bk];
            b1 = *(const bf16x8*)&Wut[(size_t)(cb + bc) * DM + kc + bk + 8];
        }
        #pragma unroll
        for (int kk = 0; kk < 2; ++kk) {
            bf16x8 bv = *(bf16x8*)&Bs[w * 16 + fr][kk * 32 + fh * 8];
            #pragma unroll
            for (int m = 0; m < 2; ++m) {
                bf16x8 av = *(bf16x8*)&As[m * 16 + fr][kk * 32 + fh * 8];
                acc[m] = __builtin_amdgcn_mfma_f32_16x16x32_bf16(av, bv, acc[m], 0, 0, 0);
            }
        }
    }
    #pragma unroll
    for (int m = 0; m < 2; ++m)
        #pragma unroll
        for (int r = 0; r < 4; ++r)
            xproj[(size_t)(row0 + m * 16 + fh * 4 + r) * DH + cb + w * 16 + fr] =
                acc[m][r];
}

// ---------------- Kernel C: gather latb + h=gelu(lat@W1) MFMA + dot + act + accumulate ----------------
// Round-7 structure; staging reads the bf16 lat table (half the random bytes, no convert).
__global__ __launch_bounds__(256) void k_gather(const float* __restrict__ xproj,
                                                const float* __restrict__ scores,
                                                const int* __restrict__ idx,
                                                const unsigned short* __restrict__ latb,
                                                const unsigned short* __restrict__ W1T,
                                                unsigned short* __restrict__ accout) {
    __shared__ unsigned short As[HK][72];    // 32 sel x 64 latent bf16 (+8 pad)
    __shared__ float Hs[HK][132];            // 32 sel x 128 hidden fp32 (+4 pad)
    __shared__ float xp[132];
    __shared__ float acts[HK];
    __shared__ float psum[DH];
    const int n = blockIdx.x;
    const int t = threadIdx.x;
    const int w = t >> 6, l = t & 63;
    const int fr = l & 15, fh = l >> 4;

    // Phase A: gather latb rows -> LDS (straight bf16 copy); xp; W1T B-frags
    {
        const int row = t >> 3, c = (t & 7) * 8;
        const int e = idx[n * HK + row];         // 8-way broadcast
        *(bf16x8*)&As[row][c] = *(const bf16x8*)&latb[(size_t)e * DL + c];
    }
    if (t < 128) xp[t] = xproj[(size_t)n * DH + t];
    bf16x8 bv[2][2];                          // [n2][kk]
    #pragma unroll
    for (int n2 = 0; n2 < 2; ++n2)
        #pragma unroll
        for (int kk = 0; kk < 2; ++kk)
            bv[n2][kk] = *(const bf16x8*)
                &W1T[(size_t)(w * 32 + n2 * 16 + fr) * DL + kk * 32 + fh * 8];
    __syncthreads();

    // Phase B: h = gelu(lat @ W1): M=32, N=128, K=64; wave w -> cols w*32
    f32x4 acc[2][2] = {};
    #pragma unroll
    for (int kk = 0; kk < 2; ++kk)
        #pragma unroll
        for (int m = 0; m < 2; ++m) {
            bf16x8 av = *(bf16x8*)&As[m * 16 + fr][kk * 32 + fh * 8];
            #pragma unroll
            for (int n2 = 0; n2 < 2; ++n2)
                acc[m][n2] = __builtin_amdgcn_mfma_f32_16x16x32_bf16(
                    av, bv[n2][kk], acc[m][n2], 0, 0, 0);
        }
    #pragma unroll
    for (int m = 0; m < 2; ++m)
        #pragma unroll
        for (int n2 = 0; n2 < 2; ++n2)
            #pragma unroll
            for (int r = 0; r < 4; ++r)
                Hs[m * 16 + fh * 4 + r][w * 32 + n2 * 16 + fr] =
                    gelu_sig(acc[m][n2][r]);
    __syncthreads();

    // Phase C: dots. s = t>>3 (32 sels), j = t&7 owns f = j*16..+15.
    {
        const int s = t >> 3, j = t & 7, f0 = j * 16;
        float part = 0.0f;
        #pragma unroll
        for (int k = 0; k < 4; ++k) {
            float4 hv = *(float4*)&Hs[s][f0 + k * 4];
            float4 xv = *(float4*)&xp[f0 + k * 4];
            part = fmaf(hv.x, xv.x, part);
            part = fmaf(hv.y, xv.y, part);
            part = fmaf(hv.z, xv.z, part);
            part = fmaf(hv.w, xv.w, part);
        }
        part += __shfl_xor(part, 1, 64);
        part += __shfl_xor(part, 2, 64);
        part += __shfl_xor(part, 4, 64);
        float a = gelu_sig(part) * scores[n * HK + s];
        if (j == 0) acts[s] = a;
    }
    __syncthreads();

    // Phase D: accout[f] = bf16(sum_s acts[s]*Hs[s][f]); f = t&127, half hh = t>>7.
    {
        const int f = t & 127, hh = t >> 7;
        float a = 0.0f;
        #pragma unroll
        for (int s8 = 0; s8 < 16; ++s8) {
            int s = hh * 16 + s8;
            a = fmaf(acts[s], Hs[s][f], a);
        }
        if (hh) psum[f] = a;
        __syncthreads();
        if (!hh) accout[(size_t)n * DH + f] = f2bf(a + psum[f]);
    }
}

// ---------------- Kernel D: out = (acc @ Wv)/4 via bf16 MFMA (bf16 acc input) ----------------
__global__ __launch_bounds__(256) void k_out(const unsigned short* __restrict__ acc,
                                             const float* __restrict__ Wv,
                                             float* __restrict__ out) {
    __shared__ unsigned short As[64][136];   // 64 rows x 128 k (+8 pad)
    const int t = threadIdx.x;
    const int w = t >> 6, l = t & 63;
    const int fr = l & 15, fh = l >> 4;
    const int row0 = blockIdx.x * 64;
    const int c0 = blockIdx.y * 128;
    const int ar = t >> 2, ac = (t & 3) * 32;    // 32 bf16/thread (64x128)

    {
        const unsigned short* src = &acc[(size_t)(row0 + ar) * DH + ac];
        *(bf16x8*)&As[ar][ac]      = *(const bf16x8*)&src[0];
        *(bf16x8*)&As[ar][ac + 8]  = *(const bf16x8*)&src[8];
        *(bf16x8*)&As[ar][ac + 16] = *(const bf16x8*)&src[16];
        *(bf16x8*)&As[ar][ac + 24] = *(const bf16x8*)&src[24];
    }
    bf16x8 bv[2][4];
    #pragma unroll
    for (int n = 0; n < 2; ++n)
        #pragma unroll
        for (int kk = 0; kk < 4; ++kk)
            #pragma unroll
            for (int b = 0; b < 8; ++b)
                bv[n][kk][b] = (short)f2bf(
                    Wv[(size_t)(kk * 32 + fh * 8 + b) * DM + c0 + w * 32 + n * 16 + fr]);
    __syncthreads();

    f32x4 o[4][2] = {};
    #pragma unroll
    for (int kk = 0; kk < 4; ++kk)
        #pragma unroll
        for (int m = 0; m < 4; ++m) {
            bf16x8 av = *(bf16x8*)&As[m * 16 + fr][kk * 32 + fh * 8];
            #pragma unroll
            for (int n = 0; n < 2; ++n)
                o[m][n] = __builtin_amdgcn_mfma_f32_16x16x32_bf16(
                    av, bv[n][kk], o[m][n], 0, 0, 0);
        }
    #pragma unroll
    for (int m = 0; m < 4; ++m)
        #pragma unroll
        for (int n = 0; n < 2; ++n)
            #pragma unroll
            for (int r = 0; r < 4; ++r)
                out[(size_t)(row0 + m * 16 + fh * 4 + r) * DM + c0 + w * 32 + n * 16 + fr] =
                    o[m][n][r] * 0.25f;
}

extern "C" void kernel_launch(void* const* d_in, const int* in_sizes, int n_in,
                              void* d_out, int out_size, void* d_ws, size_t ws_size,
                              hipStream_t stream) {
    const float* x      = (const float*)d_in[0];
    const float* scores = (const float*)d_in[1];
    const int*   idx    = (const int*)d_in[2];
    const float* lat    = (const float*)d_in[3];
    const float* W1     = (const float*)d_in[4];
    const float* Wu     = (const float*)d_in[5];
    const float* Wv     = (const float*)d_in[6];
    float* out = (float*)d_out;

    float* xproj = (float*)d_ws;                                   // 4 MB
    unsigned short* accbuf = (unsigned short*)(xproj + (size_t)NTOK * DH);  // 2 MB bf16
    unsigned short* Wut  = accbuf + (size_t)NTOK * DH;             // 256 KB
    unsigned short* W1T  = Wut + (size_t)DH * DM;                  // 16 KB
    unsigned short* latb = W1T + (size_t)DH * DL;                  // 8.4 MB bf16

    k_prep<<<544 + (NEXP * DL / 8) / 256, 256, 0, stream>>>(Wu, W1, lat, Wut, W1T, latb);
    k_xproj<<<dim3(NTOK / 32, 2), 256, 0, stream>>>(x, Wut, xproj);
    k_gather<<<NTOK, 256, 0, stream>>>(xproj, scores, idx, latb, W1T, accbuf);
    k_out<<<dim3(NTOK / 64, DM / 128), 256, 0, stream>>>(accbuf, Wv, out);
}

// Round 11
// 59.348 us; speedup vs baseline: 1.2240x; 1.0144x over previous
//
#include <hip/hip_runtime.h>
#include <hip/hip_bf16.h>

#define DM   1024
#define DH   128
#define DL   64
#define NTOK 8192
#define NEXP 65536
#define HK   32

typedef __attribute__((ext_vector_type(4))) float f32x4;
typedef __attribute__((ext_vector_type(8))) short bf16x8;

__device__ __forceinline__ float gelu_sig(float v) {
    return v * __builtin_amdgcn_rcpf(1.0f + __expf(-1.702f * v));
}

__device__ __forceinline__ unsigned short f2bf(float f) {
    union { float f; unsigned u; } v; v.f = f;
    unsigned r = v.u + 0x7FFFu + ((v.u >> 16) & 1u);   // RNE
    return (unsigned short)(r >> 16);
}

__device__ __forceinline__ bf16x8 pack8(const float4& a, const float4& b) {
    bf16x8 r;
    r[0] = (short)f2bf(a.x); r[1] = (short)f2bf(a.y);
    r[2] = (short)f2bf(a.z); r[3] = (short)f2bf(a.w);
    r[4] = (short)f2bf(b.x); r[5] = (short)f2bf(b.y);
    r[6] = (short)f2bf(b.z); r[7] = (short)f2bf(b.w);
    return r;
}

// ---------------- Kernel P: Wut/W1T transposed bf16 tables + latb bf16 table ----------------
__global__ __launch_bounds__(256) void k_prep(const float* __restrict__ Wu,
                                              const float* __restrict__ W1,
                                              const float* __restrict__ lat,
                                              unsigned short* __restrict__ Wut,
                                              unsigned short* __restrict__ W1T,
                                              unsigned short* __restrict__ latb) {
    const int b = blockIdx.x, t = threadIdx.x;
    if (b < 512) {                       // Wut: 128 x 1024 (transpose)
        const int i = b * 256 + t;
        const int c = i >> 10, k = i & 1023;
        Wut[i] = f2bf(Wu[k * DH + c]);
    } else if (b < 544) {                // W1T: 128 x 64 (transpose)
        const int j = (b - 512) * 256 + t;
        const int c = j >> 6, k = j & 63;
        W1T[j] = f2bf(W1[k * DH + c]);
    } else {                             // latb: straight bf16 convert, 8 elems/thread
        const size_t base = ((size_t)(b - 544) * 256 + t) * 8;
        float4 v0 = *(const float4*)&lat[base];
        float4 v1 = *(const float4*)&lat[base + 4];
        *(bf16x8*)&latb[base] = pack8(v0, v1);
    }
}

// ---------------- Kernel A: xproj partials, split-K ----------------
// grid (NTOK/32, 2): block = 32 rows x 128 cols x K-half (512). x read ONCE total.
// Wave w -> cols w*32 (N_rep=2), M_rep=2.
__global__ __launch_bounds__(256) void k_xproj(const float* __restrict__ x,
                                               const unsigned short* __restrict__ Wut,
                                               float* __restrict__ xpart) {
    __shared__ unsigned short As[32][72];    // 32 rows x 64 k (+8 pad)
    __shared__ unsigned short Bs[128][72];   // 128 cols x 64 k (+8 pad)
    const int t = threadIdx.x;
    const int w = t >> 6, l = t & 63;
    const int fr = l & 15, fh = l >> 4;
    const int row0 = blockIdx.x * 32;
    const int ks = blockIdx.y;
    const int k0 = ks * (DM / 2);
    const int ar = t >> 3, ac = (t & 7) * 8;     // A: 8 floats/thread (32x64)
    const int bc = t >> 1, bk = (t & 1) * 32;    // B: 32 bf16/thread (128x64)

    f32x4 acc[2][2] = {};                    // [m][n2]
    float4 a0, a1; bf16x8 b0, b1, b2, b3;

    a0 = *(const float4*)&x[(size_t)(row0 + ar) * DM + k0 + ac];
    a1 = *(const float4*)&x[(size_t)(row0 + ar) * DM + k0 + ac + 4];
    b0 = *(const bf16x8*)&Wut[(size_t)bc * DM + k0 + bk];
    b1 = *(const bf16x8*)&Wut[(size_t)bc * DM + k0 + bk + 8];
    b2 = *(const bf16x8*)&Wut[(size_t)bc * DM + k0 + bk + 16];
    b3 = *(const bf16x8*)&Wut[(size_t)bc * DM + k0 + bk + 24];

    for (int it = 0; it < 8; ++it) {
        if (it) __syncthreads();
        *(bf16x8*)&As[ar][ac]      = pack8(a0, a1);
        *(bf16x8*)&Bs[bc][bk]      = b0;
        *(bf16x8*)&Bs[bc][bk + 8]  = b1;
        *(bf16x8*)&Bs[bc][bk + 16] = b2;
        *(bf16x8*)&Bs[bc][bk + 24] = b3;
        __syncthreads();
        if (it < 7) {
            const int kc = k0 + (it + 1) * 64;
            a0 = *(const float4*)&x[(size_t)(row0 + ar) * DM + kc + ac];
            a1 = *(const float4*)&x[(size_t)(row0 + ar) * DM + kc + ac + 4];
            b0 = *(const bf16x8*)&Wut[(size_t)bc * DM + kc + bk];
            b1 = *(const bf16x8*)&Wut[(size_t)bc * DM + kc + bk + 8];
            b2 = *(const bf16x8*)&Wut[(size_t)bc * DM + kc + bk + 16];
            b3 = *(const bf16x8*)&Wut[(size_t)bc * DM + kc + bk + 24];
        }
        #pragma unroll
        for (int kk = 0; kk < 2; ++kk) {
            bf16x8 bv[2];
            #pragma unroll
            for (int n2 = 0; n2 < 2; ++n2)
                bv[n2] = *(bf16x8*)&Bs[w * 32 + n2 * 16 + fr][kk * 32 + fh * 8];
            #pragma unroll
            for (int m = 0; m < 2; ++m) {
                bf16x8 av = *(bf16x8*)&As[m * 16 + fr][kk * 32 + fh * 8];
                #pragma unroll
                for (int n2 = 0; n2 < 2; ++n2)
                    acc[m][n2] = __builtin_amdgcn_mfma_f32_16x16x32_bf16(
                        av, bv[n2], acc[m][n2], 0, 0, 0);
            }
        }
    }
    float* dst = xpart + (size_t)ks * NTOK * DH;
    #pragma unroll
    for (int m = 0; m < 2; ++m)
        #pragma unroll
        for (int n2 = 0; n2 < 2; ++n2)
            #pragma unroll
            for (int r = 0; r < 4; ++r)
                dst[(size_t)(row0 + m * 16 + fh * 4 + r) * DH + w * 32 + n2 * 16 + fr] =
                    acc[m][n2][r];
}

// ---------------- Kernel C: gather latb + MFMA h + fragment-domain dot/accumulate ----------------
// h layout per lane l=(fr,fh) of wave w: acc[m][n2][r] = h[s][f],
//   s = m*16 + fh*4 + r,  f = w*32 + n2*16 + fr.
__global__ __launch_bounds__(256) void k_gather(const float* __restrict__ xpart,
                                                const float* __restrict__ scores,
                                                const int* __restrict__ idx,
                                                const unsigned short* __restrict__ latb,
                                                const unsigned short* __restrict__ W1T,
                                                unsigned short* __restrict__ accout) {
    __shared__ unsigned short As[HK][72];    // 32 sel x 64 latent bf16 (+8 pad)
    __shared__ float xp[DH];
    __shared__ float pw[4][HK];              // per-wave dot partials
    __shared__ float acts[HK];
    const int n = blockIdx.x;
    const int t = threadIdx.x;
    const int w = t >> 6, l = t & 63;
    const int fr = l & 15, fh = l >> 4;

    // Phase A: gather latb rows -> LDS; xp = sum of split-K partials; W1T B-frags
    {
        const int row = t >> 3, c = (t & 7) * 8;
        const int e = idx[n * HK + row];         // 8-way broadcast
        *(bf16x8*)&As[row][c] = *(const bf16x8*)&latb[(size_t)e * DL + c];
    }
    if (t < 128)
        xp[t] = xpart[(size_t)n * DH + t] + xpart[(size_t)NTOK * DH + (size_t)n * DH + t];
    bf16x8 bv[2][2];                          // [n2][kk]
    #pragma unroll
    for (int n2 = 0; n2 < 2; ++n2)
        #pragma unroll
        for (int kk = 0; kk < 2; ++kk)
            bv[n2][kk] = *(const bf16x8*)
                &W1T[(size_t)(w * 32 + n2 * 16 + fr) * DL + kk * 32 + fh * 8];
    __syncthreads();

    // Phase B: h = gelu(lat @ W1), kept in registers
    f32x4 acc[2][2] = {};
    #pragma unroll
    for (int kk = 0; kk < 2; ++kk)
        #pragma unroll
        for (int m = 0; m < 2; ++m) {
            bf16x8 av = *(bf16x8*)&As[m * 16 + fr][kk * 32 + fh * 8];
            #pragma unroll
            for (int n2 = 0; n2 < 2; ++n2)
                acc[m][n2] = __builtin_amdgcn_mfma_f32_16x16x32_bf16(
                    av, bv[n2][kk], acc[m][n2], 0, 0, 0);
        }
    #pragma unroll
    for (int m = 0; m < 2; ++m)
        #pragma unroll
        for (int n2 = 0; n2 < 2; ++n2)
            #pragma unroll
            for (int r = 0; r < 4; ++r)
                acc[m][n2][r] = gelu_sig(acc[m][n2][r]);

    // Phase C: dot partials from fragments. xpv[n2] = xp[f(n2)].
    {
        float xpv[2];
        #pragma unroll
        for (int n2 = 0; n2 < 2; ++n2) xpv[n2] = xp[w * 32 + n2 * 16 + fr];
        float p[2][4];
        #pragma unroll
        for (int m = 0; m < 2; ++m)
            #pragma unroll
            for (int r = 0; r < 4; ++r) {
                float v = acc[m][0][r] * xpv[0];
                v = fmaf(acc[m][1][r], xpv[1], v);
                v += __shfl_xor(v, 1, 64);
                v += __shfl_xor(v, 2, 64);
                v += __shfl_xor(v, 4, 64);
                v += __shfl_xor(v, 8, 64);
                p[m][r] = v;
            }
        if (fr == 0) {
            #pragma unroll
            for (int m = 0; m < 2; ++m)
                #pragma unroll
                for (int r = 0; r < 4; ++r)
                    pw[w][m * 16 + fh * 4 + r] = p[m][r];
        }
    }
    __syncthreads();

    // Phase C2: acts[s] = gelu(sum_w pw) * score
    if (t < HK) {
        float d = pw[0][t] + pw[1][t] + pw[2][t] + pw[3][t];
        acts[t] = gelu_sig(d) * scores[n * HK + t];
    }
    __syncthreads();

    // Phase D: accout[f] = bf16(sum_s acts[s]*h[s][f]) from fragments.
    {
        float am[2][4];
        #pragma unroll
        for (int m = 0; m < 2; ++m)
            #pragma unroll
            for (int r = 0; r < 4; ++r)
                am[m][r] = acts[m * 16 + fh * 4 + r];   // LDS broadcast within fh-group
        #pragma unroll
        for (int n2 = 0; n2 < 2; ++n2) {
            float a = 0.0f;
            #pragma unroll
            for (int m = 0; m < 2; ++m)
                #pragma unroll
                for (int r = 0; r < 4; ++r)
                    a = fmaf(am[m][r], acc[m][n2][r], a);
            a += __shfl_xor(a, 16, 64);
            a += __shfl_xor(a, 32, 64);
            if (fh == 0)
                accout[(size_t)n * DH + w * 32 + n2 * 16 + fr] = f2bf(a);
        }
    }
}

// ---------------- Kernel D: out = (acc @ Wv)/4 via bf16 MFMA (bf16 acc input) ----------------
__global__ __launch_bounds__(256) void k_out(const unsigned short* __restrict__ acc,
                                             const float* __restrict__ Wv,
                                             float* __restrict__ out) {
    __shared__ unsigned short As[64][136];   // 64 rows x 128 k (+8 pad)
    const int t = threadIdx.x;
    const int w = t >> 6, l = t & 63;
    const int fr = l & 15, fh = l >> 4;
    const int row0 = blockIdx.x * 64;
    const int c0 = blockIdx.y * 128;
    const int ar = t >> 2, ac = (t & 3) * 32;    // 32 bf16/thread (64x128)

    {
        const unsigned short* src = &acc[(size_t)(row0 + ar) * DH + ac];
        *(bf16x8*)&As[ar][ac]      = *(const bf16x8*)&src[0];
        *(bf16x8*)&As[ar][ac + 8]  = *(const bf16x8*)&src[8];
        *(bf16x8*)&As[ar][ac + 16] = *(const bf16x8*)&src[16];
        *(bf16x8*)&As[ar][ac + 24] = *(const bf16x8*)&src[24];
    }
    bf16x8 bv[2][4];
    #pragma unroll
    for (int n = 0; n < 2; ++n)
        #pragma unroll
        for (int kk = 0; kk < 4; ++kk)
            #pragma unroll
            for (int b = 0; b < 8; ++b)
                bv[n][kk][b] = (short)f2bf(
                    Wv[(size_t)(kk * 32 + fh * 8 + b) * DM + c0 + w * 32 + n * 16 + fr]);
    __syncthreads();

    f32x4 o[4][2] = {};
    #pragma unroll
    for (int kk = 0; kk < 4; ++kk)
        #pragma unroll
        for (int m = 0; m < 4; ++m) {
            bf16x8 av = *(bf16x8*)&As[m * 16 + fr][kk * 32 + fh * 8];
            #pragma unroll
            for (int n = 0; n < 2; ++n)
                o[m][n] = __builtin_amdgcn_mfma_f32_16x16x32_bf16(
                    av, bv[n][kk], o[m][n], 0, 0, 0);
        }
    #pragma unroll
    for (int m = 0; m < 4; ++m)
        #pragma unroll
        for (int n = 0; n < 2; ++n)
            #pragma unroll
            for (int r = 0; r < 4; ++r)
                out[(size_t)(row0 + m * 16 + fh * 4 + r) * DM + c0 + w * 32 + n * 16 + fr] =
                    o[m][n][r] * 0.25f;
}

extern "C" void kernel_launch(void* const* d_in, const int* in_sizes, int n_in,
                              void* d_out, int out_size, void* d_ws, size_t ws_size,
                              hipStream_t stream) {
    const float* x      = (const float*)d_in[0];
    const float* scores = (const float*)d_in[1];
    const int*   idx    = (const int*)d_in[2];
    const float* lat    = (const float*)d_in[3];
    const float* W1     = (const float*)d_in[4];
    const float* Wu     = (const float*)d_in[5];
    const float* Wv     = (const float*)d_in[6];
    float* out = (float*)d_out;

    float* xpart = (float*)d_ws;                                   // 2 x 4 MB
    unsigned short* accbuf = (unsigned short*)(xpart + (size_t)2 * NTOK * DH);  // 2 MB bf16
    unsigned short* Wut  = accbuf + (size_t)NTOK * DH;             // 256 KB
    unsigned short* W1T  = Wut + (size_t)DH * DM;                  // 16 KB
    unsigned short* latb = W1T + (size_t)DH * DL;                  // 8.4 MB bf16

    k_prep<<<544 + (NEXP * DL / 8) / 256, 256, 0, stream>>>(Wu, W1, lat, Wut, W1T, latb);
    k_xproj<<<dim3(NTOK / 32, 2), 256, 0, stream>>>(x, Wut, xpart);
    k_gather<<<NTOK, 256, 0, stream>>>(xpart, scores, idx, latb, W1T, accbuf);
    k_out<<<dim3(NTOK / 64, DM / 128), 256, 0, stream>>>(accbuf, Wv, out);
}